// Round 15
// baseline (219.652 us; speedup 1.0000x reference)
//
#include <hip/hip_runtime.h>

typedef __attribute__((ext_vector_type(8))) short bf16x8;
typedef __attribute__((ext_vector_type(4))) float f32x4;
typedef __attribute__((ext_vector_type(2))) unsigned int u32x2;

#define NBLK 1024
#define NTHR 512    // 8 waves/block; 3 blocks/CU resident (48 KB LDS each)
#define NT   32     // 16-row tiles: 1024 blocks * 32 * 16 = 524288 rows
#define DOUT 128

__device__ __forceinline__ unsigned short bf_rne(float x) {
  unsigned u = __builtin_bit_cast(unsigned, x);
  return (unsigned short)((u + 0x7FFFu + ((u >> 16) & 1u)) >> 16);
}
// fp32 -> bf16 hi (truncate) + bf16 lo (RNE of residual); x ~ hi+lo to ~2^-15 rel
__device__ __forceinline__ void split2(float x, short& hi, short& lo) {
  unsigned u = __builtin_bit_cast(unsigned, x);
  float hf = __builtin_bit_cast(float, u & 0xFFFF0000u);
  hi = (short)(unsigned short)(u >> 16);
  lo = (short)bf_rne(x - hf);
}
__device__ __forceinline__ unsigned pk(short a, short b) {
  return (unsigned)(unsigned short)a | ((unsigned)(unsigned short)b << 16);
}
// async global->LDS, 16B/lane, per-lane global src + wave-uniform LDS base
__device__ __forceinline__ void gll16(const float* g, char* l) {
  __builtin_amdgcn_global_load_lds(
      (const __attribute__((address_space(1))) unsigned int*)g,
      (__attribute__((address_space(3))) unsigned int*)l, 16, 0, 0);
}

// R15: occupancy is the BW lever (R3: 29 waves -> 3.9 TB/s even while
// spilling; all clean 8-wave designs stuck at 2.3-2.9). LDS cut to 48 KB
// (3-slot ring x 16 KB) -> 3 blocks = 24 waves/CU. In-place split: slot holds
// fp32 tile (DMA dst, linear); read own-wave rows -> regs; barrier; overwrite
// SAME slot with bf16 hi/lo frag layout (8 KB + 8 KB). 3-slot rotation gives
// the DMA a full iteration of flight; vmcnt(2) counted (0 only in 2 tail
// iters). W masked/split in 32 VGPRs/wave (R2/R13-proven). (512,2) cap 128,
// body ~75. Frag read l^ks = lane permutation -> 0 conflicts (R8 class).
__global__ __launch_bounds__(NTHR, 2)
void dagmm(const float* __restrict__ x0, const float* __restrict__ x1,
           const float* __restrict__ w0, const float* __restrict__ w1,
           const float* __restrict__ m0, const float* __restrict__ m1,
           float* __restrict__ out)
{
  __shared__ __align__(16) char L[49152];   // 3 slots x 16 KB

  const int t   = threadIdx.x;
  const int l   = t & 63;
  const int w   = t >> 6;       // wave 0..7 -> owns output cols [w*16, w*16+16)
  const int l16 = l & 15;
  const int lq  = l >> 4;

  // ---------- W preamble: masked + hi/lo-split A-frags in VGPRs ----------
  bf16x8 bhi[8], blo[8];
  {
    const int col = w * 16 + l16;
#pragma unroll
    for (int ks = 0; ks < 8; ++ks) {
      const int k0 = ks * 32 + lq * 8;            // never straddles 128
      const float* wp = (k0 < 128) ? (w0 + col * 128 + k0) : (w1 + col * 128 + (k0 - 128));
      const float* mp = (k0 < 128) ? (m0 + col * 128 + k0) : (m1 + col * 128 + (k0 - 128));
      float4 wa = *(const float4*)wp, wb = *(const float4*)(wp + 4);
      float4 ma = *(const float4*)mp, mb = *(const float4*)(mp + 4);
      float v[8] = {wa.x*ma.x, wa.y*ma.y, wa.z*ma.z, wa.w*ma.w,
                    wb.x*mb.x, wb.y*mb.y, wb.z*mb.z, wb.w*mb.w};
      bf16x8 hv, lv;
#pragma unroll
      for (int j = 0; j < 8; ++j) { short h, lo2; split2(v[j], h, lo2); hv[j] = h; lv[j] = lo2; }
      bhi[ks] = hv; blo[ks] = lv;
    }
  }

  const size_t Tbase = (size_t)blockIdx.x * (NT * 16);
  // per-lane DMA source: lane covers floats [l*4, l*4+4) of a row's K=256
  const float* xsrc = (l < 32) ? (x0 + l * 4) : (x1 + (l - 32) * 4);

  // wave w DMAs rows 2w, 2w+1 of each tile (1 KB/row, lane x 16B linear)
#define ISSUE(ts, sl)                                                       \
  {                                                                         \
    _Pragma("unroll")                                                       \
    for (int i = 0; i < 2; ++i) {                                           \
      const int row = w * 2 + i;                                            \
      const size_t grow = Tbase + (size_t)(ts) * 16 + row;                  \
      gll16(xsrc + grow * 128, L + (sl) * 16384 + row * 1024);              \
    }                                                                       \
  }

  // read-phase: thread t reads ITS OWN WAVE's rows (t>>5 == 2w + (l>>5)):
  // floats k0..k0+3 and k0+128..k0+131 of row rrow
  const int rrow = t >> 5;
  const int k0   = (t & 31) * 4;
  // write-phase constants: bf16 of (rrow, k) -> hi byte addr
  //   ks*1024 + ((lam ^ ks)<<4) + (k&7)*2, lo at +8192
  const int ksA  = k0 >> 5;                              // 0..3 (rb: +4)
  const int lamA = (rrow & 15) | (((k0 >> 3) & 3) << 4);
  const int j2   = (k0 & 7) * 2;

#define WRITEPH(sl)                                                         \
  {                                                                         \
    short h0,h1,h2,h3, e0,e1,e2,e3;                                         \
    split2(ra.x, h0, e0); split2(ra.y, h1, e1);                             \
    split2(ra.z, h2, e2); split2(ra.w, h3, e3);                             \
    u32x2 hv, lv;                                                           \
    hv[0] = pk(h0, h1); hv[1] = pk(h2, h3);                                 \
    lv[0] = pk(e0, e1); lv[1] = pk(e2, e3);                                 \
    char* p = L + (sl) * 16384 + ksA * 1024 + ((lamA ^ ksA) << 4) + j2;     \
    *(u32x2*)p          = hv;                                               \
    *(u32x2*)(p + 8192) = lv;                                               \
    split2(rb.x, h0, e0); split2(rb.y, h1, e1);                             \
    split2(rb.z, h2, e2); split2(rb.w, h3, e3);                             \
    hv[0] = pk(h0, h1); hv[1] = pk(h2, h3);                                 \
    lv[0] = pk(e0, e1); lv[1] = pk(e2, e3);                                 \
    const int ksB = ksA + 4;                                                \
    char* q = L + (sl) * 16384 + ksB * 1024 + ((lamA ^ ksB) << 4) + j2;     \
    *(u32x2*)q          = hv;                                               \
    *(u32x2*)(q + 8192) = lv;                                               \
  }

  float4 ra, rb;

  // ---------- prologue: tile0 -> slot0 (split in place), tile1 -> slot1 ----
  ISSUE(0, 0);
  ISSUE(1, 1);
  asm volatile("s_waitcnt vmcnt(2)" ::: "memory");   // tile 0 landed (own rows)
  ra = *(const float4*)(L + rrow * 1024 + k0 * 4);
  rb = *(const float4*)(L + rrow * 1024 + k0 * 4 + 512);
  asm volatile("s_waitcnt lgkmcnt(0)" ::: "memory");
  __builtin_amdgcn_s_barrier();                      // all fp32 reads done
  WRITEPH(0);
  asm volatile("s_waitcnt lgkmcnt(0)" ::: "memory");
  __builtin_amdgcn_s_barrier();                      // tile0 bf16 visible

  for (int tt = 0; tt < NT; ++tt) {
    const int s0 = tt % 3, s1 = (tt + 1) % 3, s2 = (tt + 2) % 3;

    // 1) DMA tile tt+2 into s2 (its last reader, MFMA(tt-1), done at barrier2)
    if (tt + 2 < NT) {
      ISSUE(tt + 2, s2);
      asm volatile("s_waitcnt vmcnt(2)" ::: "memory");  // tt+1 landed (own rows)
    } else {
      asm volatile("s_waitcnt vmcnt(0)" ::: "memory");  // tail: drain
    }

    // 2) read-phase: own-wave fp32 rows of tile tt+1 -> regs
    if (tt + 1 < NT) {
      ra = *(const float4*)(L + s1 * 16384 + rrow * 1024 + k0 * 4);
      rb = *(const float4*)(L + s1 * 16384 + rrow * 1024 + k0 * 4 + 512);
    }

    // 3) MFMA(tt) from s0 bf16: 8 ks x {2 reads + 3 MFMA}
    f32x4 acc = (f32x4){0.f, 0.f, 0.f, 0.f};
#pragma unroll
    for (int ks = 0; ks < 8; ++ks) {
      const char* bp = L + s0 * 16384 + ks * 1024 + ((l ^ ks) << 4);
      bf16x8 xh = *(const bf16x8*)bp;
      bf16x8 xl = *(const bf16x8*)(bp + 8192);
      // W ~ bhi+blo, X ~ xh+xl: 3 terms (drop blo*xl ~2^-30)
      acc = __builtin_amdgcn_mfma_f32_16x16x32_bf16(bhi[ks], xh, acc, 0, 0, 0);
      acc = __builtin_amdgcn_mfma_f32_16x16x32_bf16(bhi[ks], xl, acc, 0, 0, 0);
      acc = __builtin_amdgcn_mfma_f32_16x16x32_bf16(blo[ks], xh, acc, 0, 0, 0);
    }

    // D (R13-verified): col(l16) = batch row, lq*4+r = out col -> f32x4
    {
      const size_t row = Tbase + (size_t)tt * 16 + l16;
      *(f32x4*)&out[row * DOUT + w * 16 + lq * 4] = acc;
    }

    // 4) barrier1: all reads (fp32 tt+1 + bf16 tt) drained before overwrite
    asm volatile("s_waitcnt lgkmcnt(0)" ::: "memory");
    __builtin_amdgcn_s_barrier();

    // 5) write-phase: bf16 hi/lo of tile tt+1 in place into s1
    if (tt + 1 < NT) WRITEPH(s1);

    // 6) barrier2: bf16 visible to all waves for MFMA(tt+1)
    asm volatile("s_waitcnt lgkmcnt(0)" ::: "memory");
    __builtin_amdgcn_s_barrier();
  }
#undef ISSUE
#undef WRITEPH
}

extern "C" void kernel_launch(void* const* d_in, const int* in_sizes, int n_in,
                              void* d_out, int out_size, void* d_ws, size_t ws_size,
                              hipStream_t stream) {
  const float* x0 = (const float*)d_in[0];
  const float* x1 = (const float*)d_in[1];
  const float* w0 = (const float*)d_in[2];
  const float* w1 = (const float*)d_in[3];
  const float* m0 = (const float*)d_in[4];
  const float* m1 = (const float*)d_in[5];
  dagmm<<<NBLK, NTHR, 0, stream>>>(x0, x1, w0, w1, m0, m1, (float*)d_out);
}

// Round 16
// 184.767 us; speedup vs baseline: 1.1888x; 1.1888x over previous
//
#include <hip/hip_runtime.h>

typedef __attribute__((ext_vector_type(8))) short bf16x8;
typedef __attribute__((ext_vector_type(4))) float f32x4;
typedef __attribute__((ext_vector_type(4))) int   i32x4;
typedef __attribute__((ext_vector_type(2))) unsigned int u32x2;

#define NBLK 1024
#define NTHR 512    // 8 waves; 64 KB LDS -> 2 blocks/CU co-resident
#define NT   32     // 16-row tiles: 1024 * 32 * 16 = 524288 rows
#define DOUT 128

__device__ __forceinline__ unsigned short bf_rne(float x) {
  unsigned u = __builtin_bit_cast(unsigned, x);
  return (unsigned short)((u + 0x7FFFu + ((u >> 16) & 1u)) >> 16);
}
// fp32 -> bf16 hi (truncate) + bf16 lo (RNE of residual); x ~ hi+lo to ~2^-15 rel
__device__ __forceinline__ void split2(float x, short& hi, short& lo) {
  unsigned u = __builtin_bit_cast(unsigned, x);
  float hf = __builtin_bit_cast(float, u & 0xFFFF0000u);
  hi = (short)(unsigned short)(u >> 16);
  lo = (short)bf_rne(x - hf);
}
__device__ __forceinline__ unsigned pk(short a, short b) {
  return (unsigned)(unsigned short)a | ((unsigned)(unsigned short)b << 16);
}
// async global->LDS, 16B/lane, per-lane global src + wave-uniform LDS base
__device__ __forceinline__ void gll16(const float* g, char* l) {
  __builtin_amdgcn_global_load_lds(
      (const __attribute__((address_space(1))) unsigned int*)g,
      (__attribute__((address_space(3))) unsigned int*)l, 16, 0, 0);
}

// MFMA with A from AGPR (W stationary), B from VGPR (x), acc in VGPR.
// s_nop 1 guards the VALU-write -> MFMA-read hazard the compiler can't see
// across the asm boundary.
#define MFMA_AW(ACC, W, X)                                                   \
  asm("s_nop 1\n\tv_mfma_f32_16x16x32_bf16 %0, %1, %2, %0"                   \
      : "+v"(ACC) : "a"(W), "v"(X))

// R16: break the occupancy pin. Empirical law from R1-R15: waves/SIMD =
// floor(512 / (2 x VGPR_Count)) — the allocator mirrors an AGPR region equal
// to arch VGPRs. W-frags (64 regs) kept ALL designs at 2 waves/SIMD. Fix:
// W lives in AGPRs (the otherwise-wasted mirror half) via "a" constraints;
// arch VGPRs ~50 -> 4-5 waves/SIMD, 2 blocks/CU (LDS 64 KB).
// Dataflow (R13-derived, 1 barrier/iter):
//   barrier -> ISSUE(tt+2) -> vmcnt(2) [own 2 rows of tt+1 landed; fixes
//   R13's latent vmcnt(6) race] -> SPLIT(tt+1) || MFMA(tt) -> lgkm(0).
// LDS banking (derived to inherent minimum): F-read lane-linear 16B;
// B-write groups spread by (row^ks); frag-read l^ks permutation (R13 class).
__global__ __launch_bounds__(NTHR, 2)
void dagmm(const float* __restrict__ x0, const float* __restrict__ x1,
           const float* __restrict__ w0, const float* __restrict__ w1,
           const float* __restrict__ m0, const float* __restrict__ m1,
           float* __restrict__ out)
{
  __shared__ __align__(16) char L[65536];
  // F[r]  = r*16384          : fp32 tile [16 rows][1024 B], row-major (DMA dst)
  // B[r]  = 32768 + r*16384  : bf16 hi plane 8 KB (ks*1024 frag-major), lo +8192

  const int t   = threadIdx.x;
  const int l   = t & 63;
  const int w   = t >> 6;       // wave 0..7 -> owns output cols [w*16, w*16+16)
  const int l16 = l & 15;
  const int lq  = l >> 4;

  // ---------- W preamble: masked + hi/lo-split A-frags -> AGPRs ----------
  i32x4 WH[8], WL[8];
  {
    const int col = w * 16 + l16;
#pragma unroll
    for (int ks = 0; ks < 8; ++ks) {
      const int k0 = ks * 32 + lq * 8;            // never straddles 128
      const float* wp = (k0 < 128) ? (w0 + col * 128 + k0) : (w1 + col * 128 + (k0 - 128));
      const float* mp = (k0 < 128) ? (m0 + col * 128 + k0) : (m1 + col * 128 + (k0 - 128));
      float4 wa = *(const float4*)wp, wb = *(const float4*)(wp + 4);
      float4 ma = *(const float4*)mp, mb = *(const float4*)(mp + 4);
      float v[8] = {wa.x*ma.x, wa.y*ma.y, wa.z*ma.z, wa.w*ma.w,
                    wb.x*mb.x, wb.y*mb.y, wb.z*mb.z, wb.w*mb.w};
      bf16x8 hv, lv;
#pragma unroll
      for (int j = 0; j < 8; ++j) { short h, lo2; split2(v[j], h, lo2); hv[j] = h; lv[j] = lo2; }
      WH[ks] = __builtin_bit_cast(i32x4, hv);
      WL[ks] = __builtin_bit_cast(i32x4, lv);
      asm volatile("" : "+a"(WH[ks]));   // pin W fragments in AGPRs
      asm volatile("" : "+a"(WL[ks]));
    }
  }

  const size_t Tbase = (size_t)blockIdx.x * (NT * 16);
  // per-lane DMA source: lane covers floats [l*4, l*4+4) of a row's K=256
  const float* xsrc = (l < 32) ? (x0 + l * 4) : (x1 + (l - 32) * 4);

  // wave w DMAs rows {w, w+8} (1 KB each; matches its own SPLIT rows)
#define ISSUE(ts, fbase)                                                     \
  {                                                                          \
    _Pragma("unroll")                                                        \
    for (int i = 0; i < 2; ++i) {                                            \
      const int row = w + i * 8;                                             \
      const size_t grow = Tbase + (size_t)(ts) * 16 + row;                   \
      gll16(xsrc + grow * 128, L + (fbase) + row * 1024);                    \
    }                                                                        \
  }

  // SPLIT: thread t reads 2x16B of F (rows w, w+8: its own wave's DMA),
  // splits, writes hi/lo u32x2 pairs into B (frag-major, (row^ks)-spread)
#define SPLIT(fbase, bbase)                                                  \
  {                                                                          \
    const float4 ra = *(const float4*)(L + (fbase) + t * 16);                \
    const float4 rb = *(const float4*)(L + (fbase) + t * 16 + 8192);         \
    const int ks   = (t & 63) >> 3;                                          \
    const int oct  = ((t & 63) >> 1) & 3;                                    \
    const int half = (t & 1) * 8;                                            \
    short h0,h1,h2,h3, e0,e1,e2,e3;                                          \
    u32x2 hv, lv;                                                            \
    { /* chunk 1: row = t>>6 (== w) */                                       \
      split2(ra.x, h0, e0); split2(ra.y, h1, e1);                            \
      split2(ra.z, h2, e2); split2(ra.w, h3, e3);                            \
      hv[0] = pk(h0, h1); hv[1] = pk(h2, h3);                                \
      lv[0] = pk(e0, e1); lv[1] = pk(e2, e3);                                \
      const int lam = (t >> 6) | (oct << 4);                                 \
      char* p = L + (bbase) + ks * 1024 + (((lam ^ ks)) << 4) + half;        \
      *(u32x2*)p          = hv;                                              \
      *(u32x2*)(p + 8192) = lv;                                              \
    }                                                                        \
    { /* chunk 2: row = 8 + (t>>6) */                                        \
      split2(rb.x, h0, e0); split2(rb.y, h1, e1);                            \
      split2(rb.z, h2, e2); split2(rb.w, h3, e3);                            \
      hv[0] = pk(h0, h1); hv[1] = pk(h2, h3);                                \
      lv[0] = pk(e0, e1); lv[1] = pk(e2, e3);                                \
      const int lam = (8 + (t >> 6)) | (oct << 4);                           \
      char* p = L + (bbase) + ks * 1024 + (((lam ^ ks)) << 4) + half;        \
      *(u32x2*)p          = hv;                                              \
      *(u32x2*)(p + 8192) = lv;                                              \
    }                                                                        \
  }

  // ---------- prologue: tiles 0,1 in flight; tile0 split -> B0 ----------
  ISSUE(0, 0);
  ISSUE(1, 16384);
  asm volatile("s_waitcnt vmcnt(2)" ::: "memory");   // own rows of tile 0 landed
  SPLIT(0, 32768);
  asm volatile("s_waitcnt lgkmcnt(0)" ::: "memory");

  for (int tt = 0; tt < NT; ++tt) {
    const int r = tt & 1;

    // barrier: B[r] (tile tt) complete across all waves; F[r] fully consumed
    asm volatile("" ::: "memory");
    __builtin_amdgcn_s_barrier();
    asm volatile("" ::: "memory");

    // 1) DMA tile tt+2 into F[r] (clamped tail keeps vmcnt uniform)
    { const int ts = (tt + 2 < NT) ? (tt + 2) : (NT - 1); ISSUE(ts, r * 16384); }

    // 2) own rows of tile tt+1 landed; tt+2's 2 loads stay in flight
    asm volatile("s_waitcnt vmcnt(2)" ::: "memory");

    // 3) SPLIT(tt+1) -> B[r^1]   ||   MFMA(tt) from B[r]
    if (tt + 1 < NT) SPLIT((r ^ 1) * 16384, 32768 + (r ^ 1) * 16384);

    f32x4 acc = (f32x4){0.f, 0.f, 0.f, 0.f};
    {
      const char* Bb = L + 32768 + r * 16384;
#pragma unroll
      for (int ks = 0; ks < 8; ++ks) {
        const char* bp = Bb + ks * 1024 + ((l ^ ks) << 4);
        i32x4 xh = *(const i32x4*)bp;
        i32x4 xl = *(const i32x4*)(bp + 8192);
        // W ~ WH+WL, X ~ xh+xl: 3 terms (drop WL*xl ~2^-30)
        MFMA_AW(acc, WH[ks], xh);
        MFMA_AW(acc, WH[ks], xl);
        MFMA_AW(acc, WL[ks], xh);
      }
    }
    asm volatile("s_nop 7\n\ts_nop 7" :::);   // MFMA-write -> VALU/store hazard

    // D (R13-verified): col(l16) = batch row, lq*4+r = out col -> f32x4
    {
      const size_t row = Tbase + (size_t)tt * 16 + l16;
      *(f32x4*)&out[row * DOUT + w * 16 + lq * 4] = acc;
    }

    // 4) drain ds ops only; global loads (tt+2) stay in flight
    asm volatile("s_waitcnt lgkmcnt(0)" ::: "memory");
  }
#undef ISSUE
#undef SPLIT
}

extern "C" void kernel_launch(void* const* d_in, const int* in_sizes, int n_in,
                              void* d_out, int out_size, void* d_ws, size_t ws_size,
                              hipStream_t stream) {
  const float* x0 = (const float*)d_in[0];
  const float* x1 = (const float*)d_in[1];
  const float* w0 = (const float*)d_in[2];
  const float* w1 = (const float*)d_in[3];
  const float* m0 = (const float*)d_in[4];
  const float* m1 = (const float*)d_in[5];
  dagmm<<<NBLK, NTHR, 0, stream>>>(x0, x1, w0, w1, m0, m1, (float*)d_out);
}